// Round 4
// baseline (6931.419 us; speedup 1.0000x reference)
//
#include <hip/hip_runtime.h>
#include <stdint.h>

typedef unsigned short u16;
typedef unsigned int   u32;
typedef __attribute__((ext_vector_type(8))) short  short8;  // 8 bf16 (4 VGPRs)
typedef __attribute__((ext_vector_type(4))) float  float4v; // MFMA C/D

#define MFMA16(a,b,c) __builtin_amdgcn_mfma_f32_16x16x32_bf16((a),(b),(c),0,0,0)

__device__ __forceinline__ u16 f2bf(float f) {
  u32 u = __builtin_bit_cast(u32, f);
  return (u16)((u + 0x7FFFu + ((u >> 16) & 1u)) >> 16);  // RNE
}
__device__ __forceinline__ float sigf(float x)  { return 1.0f / (1.0f + __expf(-x)); }
__device__ __forceinline__ float tanh_(float x) { return 1.0f - 2.0f / (1.0f + __expf(2.0f * x)); }

// Bounded spin with shared fuel: converts any protocol bug into a fast
// wrong-answer instead of a container-killing hang.
__device__ __forceinline__ void wait_flag_ge(u32* p, u32 v, int* fuel) {
  while (*fuel > 0) {
    if (__hip_atomic_load(p, __ATOMIC_RELAXED, __HIP_MEMORY_SCOPE_AGENT) >= v) return;
    --*fuel;
    __builtin_amdgcn_s_sleep(2);
  }
}

// ---------------------------------------------------------------------------
// prep: bf16 weight copies, pre0 = latent@Wih0^T + bih0 + bhh0, bias1, zero state+flags
// grid 512x512 = 262144 threads
// ---------------------------------------------------------------------------
__global__ __launch_bounds__(512) void prep_kernel(
    const float* __restrict__ latent, const float* __restrict__ Wih0,
    const float* __restrict__ Whh0,  const float* __restrict__ bih0,
    const float* __restrict__ bhh0,  const float* __restrict__ Wih1,
    const float* __restrict__ Whh1,  const float* __restrict__ bih1,
    const float* __restrict__ bhh1,  const float* __restrict__ Wmap,
    u16* __restrict__ Whh0b, u16* __restrict__ Wih1b, u16* __restrict__ Whh1b,
    u16* __restrict__ Wmapb, float* __restrict__ pre0, float* __restrict__ bias1,
    float* __restrict__ h0g, float* __restrict__ c0g,
    float* __restrict__ h1g, float* __restrict__ c1g, u32* __restrict__ flags)
{
  int t = blockIdx.x * 512 + threadIdx.x;  // 0..262143
  Whh0b[t] = f2bf(Whh0[t]);
  Wih1b[t] = f2bf(Wih1[t]);
  Whh1b[t] = f2bf(Whh1[t]);
  Wmapb[t] = f2bf(Wmap[t]);
  Wmapb[t + 262144] = f2bf(Wmap[t + 262144]);

  int b = t >> 10, n = t & 1023;
  const float4* lr4 = (const float4*)(latent + (size_t)b * 128);
  const float4* wr4 = (const float4*)(Wih0 + (size_t)n * 128);
  float a = bih0[n] + bhh0[n];
#pragma unroll
  for (int k = 0; k < 32; ++k) {
    float4 x = lr4[k], w = wr4[k];
    a += x.x * w.x + x.y * w.y + x.z * w.z + x.w * w.w;
  }
  pre0[t] = a;

  if (t < 65536) { h0g[t] = 0.f; c0g[t] = 0.f; h1g[t] = 0.f; c1g[t] = 0.f; }
  if (t < 1024)  bias1[t] = bih1[t] + bhh1[t];
  if (t < 2048)  flags[t] = 0;
}

// ---------------------------------------------------------------------------
// recur: persistent recurrence. 96 WGs x 512 thr (cooperative launch w/ fallback).
//   bid 0..31 : layer 0, slice s=bid>>1 (16 batches), CU q=bid&1 owns h-cols [128q,128q+128)
//   bid 32..95: layer 1, slice s=(bid-32)>>2, CU q=(bid-32)&3 owns h-cols [64q,64q+64)
// Weights register-resident (128 VGPR/lane). h exchanged via S streams + flags.
// Streams: S_l[it][b][0:256]=h bf16, [256:512]=c bf16  (131072 halfwords per step).
// L1 inner loop computes the Whh1*h1 half FIRST (data from previous step's
// gather) to hide the L0-flag wait + h0 gather latency.
// ---------------------------------------------------------------------------
__global__ __launch_bounds__(512) void recur_kernel(
    const u16* __restrict__ Whh0b, const u16* __restrict__ Wih1b,
    const u16* __restrict__ Whh1b, const float* __restrict__ pre0,
    const float* __restrict__ bias1,
    float* __restrict__ h0g, float* __restrict__ c0g,
    float* __restrict__ h1g, float* __restrict__ c1g,
    u16* __restrict__ S0, u16* __restrict__ S1,
    u32* flags, int t0, int Tc)
{
  __shared__ __attribute__((aligned(16))) u16 hb[16 * 512];  // L0: [16][256], L1: [16][512] (h0|h1)
  __shared__ float gbuf[4 * 16 * 64];                        // L1 gate combine buffer

  const int bid = blockIdx.x;
  const int tid = threadIdx.x;
  const int W = tid >> 6, L = tid & 63;
  const int lg = L >> 4, lm = L & 15;
  int fuel = 1 << 21;  // total spin budget for this thread across ALL waits

  if (bid < 32) {
    // ------------------------- layer 0 -------------------------
    const int s = bid >> 1, q = bid & 1;
    const int hq = 8 * q + W;  // this wave's h-tile (16 cols), 0..15
    short8 wr[4][8];
#pragma unroll
    for (int g = 0; g < 4; ++g)
#pragma unroll
      for (int kt = 0; kt < 8; ++kt)
        wr[g][kt] = *(const short8*)&Whh0b[(size_t)(256 * g + 16 * hq + lm) * 256 + kt * 32 + lg * 8];
    float p0[4][4];
#pragma unroll
    for (int g = 0; g < 4; ++g)
#pragma unroll
      for (int r = 0; r < 4; ++r)
        p0[g][r] = pre0[(size_t)(16 * s + 4 * lg + r) * 1024 + 256 * g + 16 * hq + lm];
    float cst[4];
#pragma unroll
    for (int r = 0; r < 4; ++r)
      cst[r] = c0g[(16 * s + 4 * lg + r) * 256 + 16 * hq + lm];
    for (int e = tid; e < 4096; e += 512) {
      int m = e >> 8, k = e & 255;
      hb[(m * 256 + k) ^ ((m & 7) << 3)] = f2bf(h0g[(16 * s + m) * 256 + k]);
    }
    __syncthreads();
    u32* myflag = flags + (s * 2 + q) * 16;
    u32* rmflag = flags + (s * 2 + (1 - q)) * 16;

    for (int it = 0; it < Tc; ++it) {
      const int tt = t0 + it;
      const size_t sb = (size_t)it * 131072;
      float4v acc[4];
#pragma unroll
      for (int g = 0; g < 4; ++g)
        acc[g] = (float4v){p0[g][0], p0[g][1], p0[g][2], p0[g][3]};
#pragma unroll
      for (int kt = 0; kt < 8; ++kt) {
        short8 af = *(const short8*)&hb[(lm * 256 + kt * 32 + lg * 8) ^ ((lm & 7) << 3)];
#pragma unroll
        for (int g = 0; g < 4; ++g) acc[g] = MFMA16(af, wr[g][kt], acc[g]);
      }
      float hnew[4];
#pragma unroll
      for (int r = 0; r < 4; ++r) {
        float iv = sigf(acc[0][r]);
        float fv = sigf(acc[1][r]);
        float gv = tanh_(acc[2][r]);
        float ov = sigf(acc[3][r]);
        float c = fv * cst[r] + iv * gv;
        cst[r] = c;
        hnew[r] = ov * tanh_(c);
      }
      __syncthreads();  // all waves done reading hb(t-1)
#pragma unroll
      for (int r = 0; r < 4; ++r) {
        int m = 4 * lg + r, col = 16 * hq + lm, b = 16 * s + m;
        u16 hv = f2bf(hnew[r]);
        hb[(m * 256 + col) ^ ((m & 7) << 3)] = hv;
        S0[sb + (size_t)b * 512 + col] = hv;
        S0[sb + (size_t)b * 512 + 256 + col] = f2bf(cst[r]);
      }
      if (it == Tc - 1) {
#pragma unroll
        for (int r = 0; r < 4; ++r) {
          int b = 16 * s + 4 * lg + r, col = 16 * hq + lm;
          h0g[b * 256 + col] = hnew[r];
          c0g[b * 256 + col] = cst[r];
        }
      }
      __syncthreads();  // drains vmcnt: stream stores complete
      if (tid == 0) {
        __hip_atomic_store(myflag, (u32)(tt + 1), __ATOMIC_RELEASE, __HIP_MEMORY_SCOPE_AGENT);
        wait_flag_ge(rmflag, (u32)(tt + 1), &fuel);
      }
      __syncthreads();
      __builtin_amdgcn_fence(__ATOMIC_ACQUIRE, "agent");
      {  // gather partner's 128 cols into hb
        const int rq = 1 - q;
#pragma unroll
        for (int x = 0; x < 2; ++x) {
          int e = x * 512 + tid;           // 0..1023 u32 chunks (16 rows x 64)
          int m = e >> 6, cp = e & 63;
          int col = 128 * rq + cp * 2;
          u32 v = *(const u32*)&S0[sb + (size_t)(16 * s + m) * 512 + col];
          *(u32*)&hb[(m * 256 + col) ^ ((m & 7) << 3)] = v;
        }
      }
      __syncthreads();
    }
  } else {
    // ------------------------- layer 1 -------------------------
    const int r1 = bid - 32;
    const int s = r1 >> 2, q = r1 & 3;
    const int hq = 4 * q + (W & 3);  // h-tile 0..15
    const int gp = (W >> 2) * 2;     // gate pair base: waves 0-3 -> {i,f}, 4-7 -> {g,o}
    short8 wi[2][8], wh[2][8];
#pragma unroll
    for (int g2 = 0; g2 < 2; ++g2)
#pragma unroll
      for (int kt = 0; kt < 8; ++kt) {
        size_t off = (size_t)(256 * (gp + g2) + 16 * hq + lm) * 256 + kt * 32 + lg * 8;
        wi[g2][kt] = *(const short8*)&Wih1b[off];
        wh[g2][kt] = *(const short8*)&Whh1b[off];
      }
    float b1[2];
#pragma unroll
    for (int g2 = 0; g2 < 2; ++g2) b1[g2] = bias1[256 * (gp + g2) + 16 * hq + lm];
    float cst[2];
#pragma unroll
    for (int x = 0; x < 2; ++x) {
      int e = tid * 2 + x;
      cst[x] = c1g[(16 * s + (e >> 6)) * 256 + 64 * q + (e & 63)];
    }
    for (int e = tid; e < 4096; e += 512) {
      int m = e >> 8, k = e & 255;
      hb[(m * 512 + 256 + k) ^ ((m & 7) << 3)] = f2bf(h1g[(16 * s + m) * 256 + k]);
    }
    __syncthreads();
    u32* myflag = flags + 512 + (s * 4 + q) * 16;

    for (int it = 0; it < Tc; ++it) {
      const int tt = t0 + it;
      const size_t sb = (size_t)it * 131072;
      float4v acc[2];
#pragma unroll
      for (int g2 = 0; g2 < 2; ++g2) acc[g2] = (float4v){b1[g2], b1[g2], b1[g2], b1[g2]};
      // ---- h1 half FIRST (hb[256:512] holds h1(tt-1) from prev step's gather)
#pragma unroll
      for (int kt = 0; kt < 8; ++kt) {  // K 256..511: h1 x Whh1
        short8 af = *(const short8*)&hb[(lm * 512 + 256 + kt * 32 + lg * 8) ^ ((lm & 7) << 3)];
#pragma unroll
        for (int g2 = 0; g2 < 2; ++g2) acc[g2] = MFMA16(af, wh[g2][kt], acc[g2]);
      }
      // ---- now wait for L0 producers of h0(tt), gather, then h0 half
      if (tid == 0) {
        wait_flag_ge(flags + (s * 2 + 0) * 16, (u32)(tt + 1), &fuel);
        wait_flag_ge(flags + (s * 2 + 1) * 16, (u32)(tt + 1), &fuel);
      }
      __syncthreads();
      __builtin_amdgcn_fence(__ATOMIC_ACQUIRE, "agent");
#pragma unroll
      for (int x = 0; x < 4; ++x) {  // gather h0(tt) full 256 cols
        int e = x * 512 + tid;       // 0..2047 u32 (16 rows x 128)
        int m = e >> 7, cp = e & 127;
        int col = cp * 2;
        u32 v = *(const u32*)&S0[sb + (size_t)(16 * s + m) * 512 + col];
        *(u32*)&hb[(m * 512 + col) ^ ((m & 7) << 3)] = v;
      }
      __syncthreads();
#pragma unroll
      for (int kt = 0; kt < 8; ++kt) {  // K 0..255: h0 x Wih1
        short8 af = *(const short8*)&hb[(lm * 512 + kt * 32 + lg * 8) ^ ((lm & 7) << 3)];
#pragma unroll
        for (int g2 = 0; g2 < 2; ++g2) acc[g2] = MFMA16(af, wi[g2][kt], acc[g2]);
      }
#pragma unroll
      for (int g2 = 0; g2 < 2; ++g2)
#pragma unroll
        for (int r = 0; r < 4; ++r)
          gbuf[(gp + g2) * 1024 + (4 * lg + r) * 64 + 16 * (W & 3) + lm] = acc[g2][r];
      __syncthreads();
#pragma unroll
      for (int x = 0; x < 2; ++x) {  // update: each thread owns 2 (b,col) cells
        int e = tid * 2 + x;
        int bl = e >> 6, cl = e & 63;
        float iv = sigf(gbuf[0 * 1024 + bl * 64 + cl]);
        float fv = sigf(gbuf[1 * 1024 + bl * 64 + cl]);
        float gv = tanh_(gbuf[2 * 1024 + bl * 64 + cl]);
        float ov = sigf(gbuf[3 * 1024 + bl * 64 + cl]);
        float c = fv * cst[x] + iv * gv;
        cst[x] = c;
        float h = ov * tanh_(c);
        int b = 16 * s + bl, gcol = 64 * q + cl;
        u16 hv = f2bf(h);
        hb[(bl * 512 + 256 + gcol) ^ ((bl & 7) << 3)] = hv;
        S1[sb + (size_t)b * 512 + gcol] = hv;
        S1[sb + (size_t)b * 512 + 256 + gcol] = f2bf(c);
        if (it == Tc - 1) { h1g[b * 256 + gcol] = h; c1g[b * 256 + gcol] = c; }
      }
      __syncthreads();  // drains stores
      if (tid == 0) {
        __hip_atomic_store(myflag, (u32)(tt + 1), __ATOMIC_RELEASE, __HIP_MEMORY_SCOPE_AGENT);
#pragma unroll
        for (int d = 1; d < 4; ++d)
          wait_flag_ge(flags + 512 + (s * 4 + ((q + d) & 3)) * 16, (u32)(tt + 1), &fuel);
      }
      __syncthreads();
      __builtin_amdgcn_fence(__ATOMIC_ACQUIRE, "agent");
#pragma unroll
      for (int d = 1; d < 4; ++d) {  // gather 3 remote h1 slabs (64 cols each)
        int rq = (q + d) & 3;
        int m = tid >> 5, cp = tid & 31;
        int col = 64 * rq + cp * 2;
        u32 v = *(const u32*)&S1[sb + (size_t)(16 * s + m) * 512 + col];
        *(u32*)&hb[(m * 512 + 256 + col) ^ ((m & 7) << 3)] = v;
      }
      __syncthreads();
    }
  }
}

// ---------------------------------------------------------------------------
// cmap: out[t] = sigmoid(fc @ Wmap^T + bmap). Per block: one (it, layer, 128-col)
// 128x128 tile, K=1024, BK=64, 4 waves, double-buffered LDS, XOR-swizzled.
// grid = 8*Tc blocks x 256 thr. A rows ARE S_l[it] contiguous (fc quirk).
// ---------------------------------------------------------------------------
__global__ __launch_bounds__(256) void cmap_kernel(
    const u16* __restrict__ S0, const u16* __restrict__ S1,
    const u16* __restrict__ Wmapb, const float* __restrict__ bmap,
    float* __restrict__ outp, int t0, int Tc)
{
  __shared__ __attribute__((aligned(16))) u16 lds[32768];  // 2 bufs x (A 8192 + B 8192) hw
  const int bid = blockIdx.x;
  const int l = bid & 1, nb = (bid >> 1) & 3, it = bid >> 3;
  const int tid = threadIdx.x;
  const int W = tid >> 6, L = tid & 63, lg = L >> 4, lm = L & 15;
  const u16* Ab = (l ? S1 : S0) + (size_t)it * 131072;  // (128 x 1024) bf16
  const u16* Bb = Wmapb + (size_t)nb * 131072;          // (128 x 1024) bf16

  short8 rA[4], rB[4];
#pragma unroll
  for (int x = 0; x < 4; ++x) {
    int c = x * 256 + tid, row = c >> 3, sl = c & 7;
    rA[x] = *(const short8*)&Ab[(size_t)row * 1024 + sl * 8];
    rB[x] = *(const short8*)&Bb[(size_t)row * 1024 + sl * 8];
  }
  float4v acc[4][4];
#pragma unroll
  for (int mi = 0; mi < 4; ++mi)
#pragma unroll
    for (int ni = 0; ni < 4; ++ni) acc[mi][ni] = (float4v){0.f, 0.f, 0.f, 0.f};

  for (int kt = 0; kt < 16; ++kt) {
    const int buf = (kt & 1) * 16384;
#pragma unroll
    for (int x = 0; x < 4; ++x) {  // write staged regs -> LDS (swizzled)
      int c = x * 256 + tid, row = c >> 3, sl = c & 7;
      int sl2 = sl ^ (row & 7);
      *(short8*)&lds[buf + row * 64 + sl2 * 8] = rA[x];
      *(short8*)&lds[buf + 8192 + row * 64 + sl2 * 8] = rB[x];
    }
    if (kt < 15) {
#pragma unroll
      for (int x = 0; x < 4; ++x) {  // prefetch next K-step
        int c = x * 256 + tid, row = c >> 3, sl = c & 7;
        rA[x] = *(const short8*)&Ab[(size_t)row * 1024 + (kt + 1) * 64 + sl * 8];
        rB[x] = *(const short8*)&Bb[(size_t)row * 1024 + (kt + 1) * 64 + sl * 8];
      }
    }
    __syncthreads();
#pragma unroll
    for (int k2 = 0; k2 < 2; ++k2) {
      short8 afr[4], bfr[4];
#pragma unroll
      for (int mi = 0; mi < 4; ++mi) {
        int row = (W & 1) * 64 + mi * 16 + lm;
        int sl2 = (k2 * 4 + lg) ^ (row & 7);
        afr[mi] = *(const short8*)&lds[buf + row * 64 + sl2 * 8];
      }
#pragma unroll
      for (int ni = 0; ni < 4; ++ni) {
        int row = (W >> 1) * 64 + ni * 16 + lm;
        int sl2 = (k2 * 4 + lg) ^ (row & 7);
        bfr[ni] = *(const short8*)&lds[buf + 8192 + row * 64 + sl2 * 8];
      }
#pragma unroll
      for (int mi = 0; mi < 4; ++mi)
#pragma unroll
        for (int ni = 0; ni < 4; ++ni)
          acc[mi][ni] = MFMA16(afr[mi], bfr[ni], acc[mi][ni]);
    }
  }
  const int ncol0 = nb * 128 + (W >> 1) * 64;
  float bm[4];
#pragma unroll
  for (int ni = 0; ni < 4; ++ni) bm[ni] = bmap[ncol0 + ni * 16 + lm];
  const size_t ob = ((size_t)(t0 + it) * 256 + l * 128) * 512;
#pragma unroll
  for (int mi = 0; mi < 4; ++mi)
#pragma unroll
    for (int ni = 0; ni < 4; ++ni)
#pragma unroll
      for (int r = 0; r < 4; ++r) {
        int row = (W & 1) * 64 + mi * 16 + 4 * lg + r;
        int col = ncol0 + ni * 16 + lm;
        outp[ob + (size_t)row * 512 + col] = sigf(acc[mi][ni][r] + bm[ni]);
      }
}

// ---------------------------------------------------------------------------
extern "C" void kernel_launch(void* const* d_in, const int* in_sizes, int n_in,
                              void* d_out, int out_size, void* d_ws, size_t ws_size,
                              hipStream_t stream)
{
  const float* latent = (const float*)d_in[0];
  const float* Wih0 = (const float*)d_in[1];
  const float* Whh0 = (const float*)d_in[2];
  const float* bih0 = (const float*)d_in[3];
  const float* bhh0 = (const float*)d_in[4];
  const float* Wih1 = (const float*)d_in[5];
  const float* Whh1 = (const float*)d_in[6];
  const float* bih1 = (const float*)d_in[7];
  const float* bhh1 = (const float*)d_in[8];
  const float* Wmap = (const float*)d_in[9];
  const float* bmap = (const float*)d_in[10];

  char* ws = (char*)d_ws;
  u16* Whh0b  = (u16*)(ws + 0);
  u16* Wih1b  = (u16*)(ws + 524288);
  u16* Whh1b  = (u16*)(ws + 1048576);
  u16* Wmapb  = (u16*)(ws + 1572864);
  float* pre0 = (float*)(ws + 2621440);
  float* bias1= (float*)(ws + 3670016);
  float* h0g  = (float*)(ws + 3674112);
  float* c0g  = (float*)(ws + 3936256);
  float* h1g  = (float*)(ws + 4198400);
  float* c1g  = (float*)(ws + 4460544);
  u32* flags  = (u32*)(ws + 4722688);
  u16* S0     = (u16*)(ws + 4730880);

  long long avail = (long long)ws_size - 4730880LL;
  int TR = (int)(avail / 524288LL);  // bytes per step for S0+S1
  if (TR > 512) TR = 512;
  if (TR < 1) TR = 1;
  u16* S1 = S0 + (size_t)TR * 131072;
  float* outp = (float*)d_out;

  prep_kernel<<<dim3(512), dim3(512), 0, stream>>>(
      latent, Wih0, Whh0, bih0, bhh0, Wih1, Whh1, bih1, bhh1, Wmap,
      Whh0b, Wih1b, Whh1b, Wmapb, pre0, bias1, h0g, c0g, h1g, c1g, flags);

  for (int t0p = 0; t0p < 512; t0p += TR) {
    int Tc = (512 - t0p < TR) ? (512 - t0p) : TR;
    void* args[] = {(void*)&Whh0b, (void*)&Wih1b, (void*)&Whh1b, (void*)&pre0,
                    (void*)&bias1, (void*)&h0g, (void*)&c0g, (void*)&h1g,
                    (void*)&c1g, (void*)&S0, (void*)&S1, (void*)&flags,
                    (void*)&t0p, (void*)&Tc};
    hipError_t err = hipLaunchCooperativeKernel((const void*)recur_kernel,
                                                dim3(96), dim3(512), args, 0, stream);
    if (err != hipSuccess) {
      (void)hipGetLastError();  // clear error state
      // Fallback: plain launch. 96 blocks <= 256 CUs, one block/CU -> co-resident
      // in practice; bounded spin fuel guarantees termination regardless.
      recur_kernel<<<dim3(96), dim3(512), 0, stream>>>(
          Whh0b, Wih1b, Whh1b, pre0, bias1, h0g, c0g, h1g, c1g, S0, S1, flags, t0p, Tc);
    }
    cmap_kernel<<<dim3(8 * Tc), dim3(256), 0, stream>>>(
        S0, S1, Wmapb, bmap, outp, t0p, Tc);
  }
}

// Round 5
// 2965.945 us; speedup vs baseline: 2.3370x; 2.3370x over previous
//
#include <hip/hip_runtime.h>
#include <stdint.h>

typedef unsigned short u16;
typedef unsigned int   u32;
typedef unsigned long long u64;
typedef __attribute__((ext_vector_type(8))) short  short8;  // 8 bf16 (4 VGPRs)
typedef __attribute__((ext_vector_type(4))) float  float4v; // MFMA C/D

#define MFMA16(a,b,c) __builtin_amdgcn_mfma_f32_16x16x32_bf16((a),(b),(c),0,0,0)

// Agent-scope relaxed atomics: sc1 per-access ops. No cache-wide fences needed:
// producer: atomic data stores -> __syncthreads (vmcnt(0) drains to MALL) ->
// atomic flag store. Consumer: poll flag -> barrier -> atomic gathers.
#define ATOMS32(p,v) __hip_atomic_store((p),(v),__ATOMIC_RELAXED,__HIP_MEMORY_SCOPE_AGENT)
#define ATOML32(p)   __hip_atomic_load((p),__ATOMIC_RELAXED,__HIP_MEMORY_SCOPE_AGENT)
#define ATOMS64(p,v) __hip_atomic_store((p),(v),__ATOMIC_RELAXED,__HIP_MEMORY_SCOPE_AGENT)
#define ATOML64(p)   __hip_atomic_load((p),__ATOMIC_RELAXED,__HIP_MEMORY_SCOPE_AGENT)

__device__ __forceinline__ u16 f2bf(float f) {
  u32 u = __builtin_bit_cast(u32, f);
  return (u16)((u + 0x7FFFu + ((u >> 16) & 1u)) >> 16);  // RNE
}
__device__ __forceinline__ float sigf(float x)  { return 1.0f / (1.0f + __expf(-x)); }
__device__ __forceinline__ float tanh_(float x) { return 1.0f - 2.0f / (1.0f + __expf(2.0f * x)); }

// Bounded spin with shared fuel; returns last seen value (for caching).
__device__ __forceinline__ u32 wait_flag_ge(u32* p, u32 v, int* fuel) {
  u32 x = ATOML32(p);
  while (x < v && *fuel > 0) {
    --*fuel;
    __builtin_amdgcn_s_sleep(2);
    x = ATOML32(p);
  }
  return x;
}

// ---------------------------------------------------------------------------
// prep: bf16 weight copies, pre0 = latent@Wih0^T + bih0 + bhh0, bias1, zero
// state+flags. Wmapb is stored with a K-PERMUTATION matching the interleaved
// (h,c)-per-col stream layout: storage pos p (0..1023) <- orig k where
// blk=p>>9, q=p&511, k = blk*512 + (q&1)*256 + (q>>1).
// ---------------------------------------------------------------------------
__global__ __launch_bounds__(512) void prep_kernel(
    const float* __restrict__ latent, const float* __restrict__ Wih0,
    const float* __restrict__ Whh0,  const float* __restrict__ bih0,
    const float* __restrict__ bhh0,  const float* __restrict__ Wih1,
    const float* __restrict__ Whh1,  const float* __restrict__ bih1,
    const float* __restrict__ bhh1,  const float* __restrict__ Wmap,
    u16* __restrict__ Whh0b, u16* __restrict__ Wih1b, u16* __restrict__ Whh1b,
    u16* __restrict__ Wmapb, float* __restrict__ pre0, float* __restrict__ bias1,
    float* __restrict__ h0g, float* __restrict__ c0g,
    float* __restrict__ h1g, float* __restrict__ c1g, u32* __restrict__ flags)
{
  int t = blockIdx.x * 512 + threadIdx.x;  // 0..262143
  Whh0b[t] = f2bf(Whh0[t]);
  Wih1b[t] = f2bf(Wih1[t]);
  Whh1b[t] = f2bf(Whh1[t]);

  {
    int d = t >> 10, p = t & 1023;
    int blk = p >> 9, qq = p & 511;
    int ksrc = blk * 512 + ((qq & 1) << 8) + (qq >> 1);
    Wmapb[t] = f2bf(Wmap[(size_t)d * 1024 + ksrc]);
    Wmapb[t + 262144] = f2bf(Wmap[(size_t)(d + 256) * 1024 + ksrc]);
  }

  int b = t >> 10, n = t & 1023;
  const float4* lr4 = (const float4*)(latent + (size_t)b * 128);
  const float4* wr4 = (const float4*)(Wih0 + (size_t)n * 128);
  float a = bih0[n] + bhh0[n];
#pragma unroll
  for (int k = 0; k < 32; ++k) {
    float4 x = lr4[k], w = wr4[k];
    a += x.x * w.x + x.y * w.y + x.z * w.z + x.w * w.w;
  }
  pre0[t] = a;

  if (t < 65536) { h0g[t] = 0.f; c0g[t] = 0.f; h1g[t] = 0.f; c1g[t] = 0.f; }
  if (t < 1024)  bias1[t] = bih1[t] + bhh1[t];
  if (t < 4096)  flags[t] = 0;
}

// ---------------------------------------------------------------------------
// recur: persistent recurrence. 96 WGs x 512 thr. __launch_bounds__(512,2)
// (2 waves/EU = 1 WG/CU) so the 128 weight-VGPRs stay register-resident.
//   bid 0..31 : layer 0, slice s=bid>>1 (16 batches), half q=bid&1 owns h-cols [128q,+128)
//   bid 32..95: layer 1, slice s=(bid-32)>>2, quarter q owns h-cols [64q,+64)
// Streams (u32 per (b,col)): S_l[it][b][col] = h_bf16 | c_bf16<<16.
// All stream traffic is agent-relaxed atomics (sc1); flags likewise; NO fences.
// Flags: L0 WG -> flags[(2s+q)*32], L1 WG -> flags[(64+4s+q)*32].
// ---------------------------------------------------------------------------
__global__ __launch_bounds__(512, 2) void recur_kernel(
    const u16* __restrict__ Whh0b, const u16* __restrict__ Wih1b,
    const u16* __restrict__ Whh1b, const float* __restrict__ pre0,
    const float* __restrict__ bias1,
    float* __restrict__ h0g, float* __restrict__ c0g,
    float* __restrict__ h1g, float* __restrict__ c1g,
    u32* __restrict__ S0, u32* __restrict__ S1,
    u32* flags, int t0, int Tc)
{
  __shared__ __attribute__((aligned(16))) u16 hb[16 * 512];  // L0: [16][256], L1: [16][512] (h0|h1)
  __shared__ float gbuf[4 * 16 * 64];                        // L1 gate combine buffer

  const int bid = blockIdx.x;
  const int tid = threadIdx.x;
  const int W = tid >> 6, L = tid & 63;
  const int lg = L >> 4, lm = L & 15;
  int fuel = 1 << 21;  // total spin budget for this thread across ALL waits

  if (bid < 32) {
    // ------------------------- layer 0 -------------------------
    const int s = bid >> 1, q = bid & 1;
    const int hq = 8 * q + W;  // this wave's h-tile (16 cols), 0..15
    short8 wr[4][8];
#pragma unroll
    for (int g = 0; g < 4; ++g)
#pragma unroll
      for (int kt = 0; kt < 8; ++kt)
        wr[g][kt] = *(const short8*)&Whh0b[(size_t)(256 * g + 16 * hq + lm) * 256 + kt * 32 + lg * 8];
    float p0[4][4];
#pragma unroll
    for (int g = 0; g < 4; ++g)
#pragma unroll
      for (int r = 0; r < 4; ++r)
        p0[g][r] = pre0[(size_t)(16 * s + 4 * lg + r) * 1024 + 256 * g + 16 * hq + lm];
    float cst[4];
#pragma unroll
    for (int r = 0; r < 4; ++r)
      cst[r] = c0g[(16 * s + 4 * lg + r) * 256 + 16 * hq + lm];
    for (int e = tid; e < 4096; e += 512) {
      int m = e >> 8, k = e & 255;
      hb[(m * 256 + k) ^ ((m & 7) << 3)] = f2bf(h0g[(16 * s + m) * 256 + k]);
    }
    __syncthreads();
    u32* myflag = flags + (s * 2 + q) * 32;
    u32* rmflag = flags + (s * 2 + (1 - q)) * 32;
    u32 pseen = 0;

    for (int it = 0; it < Tc; ++it) {
      const int tt = t0 + it;
      const size_t sb = (size_t)it * 65536;
      float4v acc[4];
#pragma unroll
      for (int g = 0; g < 4; ++g)
        acc[g] = (float4v){p0[g][0], p0[g][1], p0[g][2], p0[g][3]};
#pragma unroll
      for (int kt = 0; kt < 8; ++kt) {
        short8 af = *(const short8*)&hb[(lm * 256 + kt * 32 + lg * 8) ^ ((lm & 7) << 3)];
#pragma unroll
        for (int g = 0; g < 4; ++g) acc[g] = MFMA16(af, wr[g][kt], acc[g]);
      }
      float hnew[4];
#pragma unroll
      for (int r = 0; r < 4; ++r) {
        float iv = sigf(acc[0][r]);
        float fv = sigf(acc[1][r]);
        float gv = tanh_(acc[2][r]);
        float ov = sigf(acc[3][r]);
        float c = fv * cst[r] + iv * gv;
        cst[r] = c;
        hnew[r] = ov * tanh_(c);
      }
      __syncthreads();  // all waves done reading hb(t-1)
#pragma unroll
      for (int r = 0; r < 4; ++r) {
        int m = 4 * lg + r, col = 16 * hq + lm, b = 16 * s + m;
        u16 hv = f2bf(hnew[r]);
        u16 cv = f2bf(cst[r]);
        hb[(m * 256 + col) ^ ((m & 7) << 3)] = hv;
        ATOMS32(&S0[sb + (size_t)b * 256 + col], (u32)hv | ((u32)cv << 16));
      }
      if (it == Tc - 1) {
#pragma unroll
        for (int r = 0; r < 4; ++r) {
          int b = 16 * s + 4 * lg + r, col = 16 * hq + lm;
          h0g[b * 256 + col] = hnew[r];
          c0g[b * 256 + col] = cst[r];
        }
      }
      __syncthreads();  // drains vmcnt: atomic stream stores ack'd at MALL
      if (tid == 0) {
        ATOMS32(myflag, (u32)(tt + 1));
        if (pseen < (u32)(tt + 1)) pseen = wait_flag_ge(rmflag, (u32)(tt + 1), &fuel);
      }
      __syncthreads();
      {  // gather partner's 128 cols into hb (u64 atomic = 2 cols)
        const int rq = 1 - q;
#pragma unroll
        for (int x = 0; x < 2; ++x) {
          int e = x * 512 + tid;           // 0..1023 u64 (16 rows x 64)
          int m = e >> 6, j = e & 63;
          int col = 128 * rq + j * 2;
          u64 v = ATOML64((u64*)&S0[sb + (size_t)(16 * s + m) * 256 + col]);
          u32 hh = (u32)(v & 0xffffu) | (((u32)(v >> 32) & 0xffffu) << 16);
          *(u32*)&hb[(m * 256 + col) ^ ((m & 7) << 3)] = hh;
        }
      }
      __syncthreads();
    }
  } else {
    // ------------------------- layer 1 -------------------------
    const int r1 = bid - 32;
    const int s = r1 >> 2, q = r1 & 3;
    const int hq = 4 * q + (W & 3);  // h-tile 0..15
    const int gp = (W >> 2) * 2;     // gate pair base: waves 0-3 -> {i,f}, 4-7 -> {g,o}
    short8 wi[2][8], wh[2][8];
#pragma unroll
    for (int g2 = 0; g2 < 2; ++g2)
#pragma unroll
      for (int kt = 0; kt < 8; ++kt) {
        size_t off = (size_t)(256 * (gp + g2) + 16 * hq + lm) * 256 + kt * 32 + lg * 8;
        wi[g2][kt] = *(const short8*)&Wih1b[off];
        wh[g2][kt] = *(const short8*)&Whh1b[off];
      }
    float b1[2];
#pragma unroll
    for (int g2 = 0; g2 < 2; ++g2) b1[g2] = bias1[256 * (gp + g2) + 16 * hq + lm];
    float cst[2];
#pragma unroll
    for (int x = 0; x < 2; ++x) {
      int e = tid * 2 + x;
      cst[x] = c1g[(16 * s + (e >> 6)) * 256 + 64 * q + (e & 63)];
    }
    for (int e = tid; e < 4096; e += 512) {
      int m = e >> 8, k = e & 255;
      hb[(m * 512 + 256 + k) ^ ((m & 7) << 3)] = f2bf(h1g[(16 * s + m) * 256 + k]);
    }
    __syncthreads();
    u32* myflag = flags + (64 + s * 4 + q) * 32;
    u32 s0a = 0, s0b = 0, pw[3] = {0, 0, 0};

    for (int it = 0; it < Tc; ++it) {
      const int tt = t0 + it;
      const size_t sb = (size_t)it * 65536;
      float4v acc[2];
#pragma unroll
      for (int g2 = 0; g2 < 2; ++g2) acc[g2] = (float4v){b1[g2], b1[g2], b1[g2], b1[g2]};
      // ---- h1 half FIRST (hb[256:512] holds h1(tt-1) from prev step's gather)
#pragma unroll
      for (int kt = 0; kt < 8; ++kt) {  // K 256..511: h1 x Whh1
        short8 af = *(const short8*)&hb[(lm * 512 + 256 + kt * 32 + lg * 8) ^ ((lm & 7) << 3)];
#pragma unroll
        for (int g2 = 0; g2 < 2; ++g2) acc[g2] = MFMA16(af, wh[g2][kt], acc[g2]);
      }
      // ---- wait for L0 producers of h0(tt) (cached: L0 usually runs ahead)
      if (tid == 0) {
        if (s0a < (u32)(tt + 1)) s0a = wait_flag_ge(flags + (s * 2 + 0) * 32, (u32)(tt + 1), &fuel);
        if (s0b < (u32)(tt + 1)) s0b = wait_flag_ge(flags + (s * 2 + 1) * 32, (u32)(tt + 1), &fuel);
      }
      __syncthreads();
#pragma unroll
      for (int x = 0; x < 4; ++x) {  // gather h0(tt) full 256 cols (u64 atomics)
        int e = x * 512 + tid;       // 0..2047 u64 (16 rows x 128)
        int m = e >> 7, j = e & 127;
        int col = j * 2;
        u64 v = ATOML64((u64*)&S0[sb + (size_t)(16 * s + m) * 256 + col]);
        u32 hh = (u32)(v & 0xffffu) | (((u32)(v >> 32) & 0xffffu) << 16);
        *(u32*)&hb[(m * 512 + col) ^ ((m & 7) << 3)] = hh;
      }
      __syncthreads();
#pragma unroll
      for (int kt = 0; kt < 8; ++kt) {  // K 0..255: h0 x Wih1
        short8 af = *(const short8*)&hb[(lm * 512 + kt * 32 + lg * 8) ^ ((lm & 7) << 3)];
#pragma unroll
        for (int g2 = 0; g2 < 2; ++g2) acc[g2] = MFMA16(af, wi[g2][kt], acc[g2]);
      }
#pragma unroll
      for (int g2 = 0; g2 < 2; ++g2)
#pragma unroll
        for (int r = 0; r < 4; ++r)
          gbuf[(gp + g2) * 1024 + (4 * lg + r) * 64 + 16 * (W & 3) + lm] = acc[g2][r];
      __syncthreads();
      {  // update: each thread owns 2 ADJACENT (b,col) cells -> one u64 stream store
        int e0 = tid * 2;
        int bl = e0 >> 6, cl = e0 & 63;
        int b = 16 * s + bl, gcol = 64 * q + cl;
        u32 w32[2];
        float hs[2];
#pragma unroll
        for (int x = 0; x < 2; ++x) {
          float iv = sigf(gbuf[0 * 1024 + bl * 64 + cl + x]);
          float fv = sigf(gbuf[1 * 1024 + bl * 64 + cl + x]);
          float gv = tanh_(gbuf[2 * 1024 + bl * 64 + cl + x]);
          float ov = sigf(gbuf[3 * 1024 + bl * 64 + cl + x]);
          float c = fv * cst[x] + iv * gv;
          cst[x] = c;
          float h = ov * tanh_(c);
          hs[x] = h;
          w32[x] = (u32)f2bf(h) | ((u32)f2bf(c) << 16);
        }
        *(u32*)&hb[(bl * 512 + 256 + gcol) ^ ((bl & 7) << 3)] =
            (w32[0] & 0xffffu) | ((w32[1] & 0xffffu) << 16);
        ATOMS64((u64*)&S1[sb + (size_t)b * 256 + gcol], (u64)w32[0] | ((u64)w32[1] << 32));
        if (it == Tc - 1) {
#pragma unroll
          for (int x = 0; x < 2; ++x) {
            h1g[b * 256 + gcol + x] = hs[x];
            c1g[b * 256 + gcol + x] = cst[x] * 1.0f;
          }
        }
      }
      __syncthreads();  // drains vmcnt: atomic stream stores ack'd at MALL
      if (tid == 0) {
        ATOMS32(myflag, (u32)(tt + 1));
#pragma unroll
        for (int d = 1; d < 4; ++d) {
          int pi = (q + d) & 3;
          if (pw[d - 1] < (u32)(tt + 1))
            pw[d - 1] = wait_flag_ge(flags + (64 + s * 4 + pi) * 32, (u32)(tt + 1), &fuel);
        }
      }
      __syncthreads();
#pragma unroll
      for (int d = 1; d < 4; ++d) {  // gather 3 remote h1 slabs (64 cols each)
        int rq = (q + d) & 3;
        int m = tid >> 5, j = tid & 31;
        int col = 64 * rq + j * 2;
        u64 v = ATOML64((u64*)&S1[sb + (size_t)(16 * s + m) * 256 + col]);
        u32 hh = (u32)(v & 0xffffu) | (((u32)(v >> 32) & 0xffffu) << 16);
        *(u32*)&hb[(m * 512 + 256 + col) ^ ((m & 7) << 3)] = hh;
      }
      __syncthreads();
    }
  }
}

// ---------------------------------------------------------------------------
// cmap: out[t] = sigmoid(fc @ Wmap^T + bmap). Per block: one (it, layer, 128-col)
// 128x128 tile, K=1024, BK=64, 4 waves, double-buffered LDS, XOR-swizzled.
// A rows are contiguous 1024-u16 blocks of S_l[it] (interleaved layout;
// Wmapb's K-permutation compensates). Normal loads: kernel-boundary acquire.
// ---------------------------------------------------------------------------
__global__ __launch_bounds__(256) void cmap_kernel(
    const u32* __restrict__ S0, const u32* __restrict__ S1,
    const u16* __restrict__ Wmapb, const float* __restrict__ bmap,
    float* __restrict__ outp, int t0, int Tc)
{
  __shared__ __attribute__((aligned(16))) u16 lds[32768];  // 2 bufs x (A 8192 + B 8192) hw
  const int bid = blockIdx.x;
  const int l = bid & 1, nb = (bid >> 1) & 3, it = bid >> 3;
  const int tid = threadIdx.x;
  const int W = tid >> 6, L = tid & 63, lg = L >> 4, lm = L & 15;
  const u16* Ab = (const u16*)((l ? S1 : S0) + (size_t)it * 65536);  // (128 x 1024) bf16
  const u16* Bb = Wmapb + (size_t)nb * 131072;                       // (128 x 1024) bf16

  short8 rA[4], rB[4];
#pragma unroll
  for (int x = 0; x < 4; ++x) {
    int c = x * 256 + tid, row = c >> 3, sl = c & 7;
    rA[x] = *(const short8*)&Ab[(size_t)row * 1024 + sl * 8];
    rB[x] = *(const short8*)&Bb[(size_t)row * 1024 + sl * 8];
  }
  float4v acc[4][4];
#pragma unroll
  for (int mi = 0; mi < 4; ++mi)
#pragma unroll
    for (int ni = 0; ni < 4; ++ni) acc[mi][ni] = (float4v){0.f, 0.f, 0.f, 0.f};

  for (int kt = 0; kt < 16; ++kt) {
    const int buf = (kt & 1) * 16384;
#pragma unroll
    for (int x = 0; x < 4; ++x) {  // write staged regs -> LDS (swizzled)
      int c = x * 256 + tid, row = c >> 3, sl = c & 7;
      int sl2 = sl ^ (row & 7);
      *(short8*)&lds[buf + row * 64 + sl2 * 8] = rA[x];
      *(short8*)&lds[buf + 8192 + row * 64 + sl2 * 8] = rB[x];
    }
    if (kt < 15) {
#pragma unroll
      for (int x = 0; x < 4; ++x) {  // prefetch next K-step
        int c = x * 256 + tid, row = c >> 3, sl = c & 7;
        rA[x] = *(const short8*)&Ab[(size_t)row * 1024 + (kt + 1) * 64 + sl * 8];
        rB[x] = *(const short8*)&Bb[(size_t)row * 1024 + (kt + 1) * 64 + sl * 8];
      }
    }
    __syncthreads();
#pragma unroll
    for (int k2 = 0; k2 < 2; ++k2) {
      short8 afr[4], bfr[4];
#pragma unroll
      for (int mi = 0; mi < 4; ++mi) {
        int row = (W & 1) * 64 + mi * 16 + lm;
        int sl2 = (k2 * 4 + lg) ^ (row & 7);
        afr[mi] = *(const short8*)&lds[buf + row * 64 + sl2 * 8];
      }
#pragma unroll
      for (int ni = 0; ni < 4; ++ni) {
        int row = (W >> 1) * 64 + ni * 16 + lm;
        int sl2 = (k2 * 4 + lg) ^ (row & 7);
        bfr[ni] = *(const short8*)&lds[buf + 8192 + row * 64 + sl2 * 8];
      }
#pragma unroll
      for (int mi = 0; mi < 4; ++mi)
#pragma unroll
        for (int ni = 0; ni < 4; ++ni)
          acc[mi][ni] = MFMA16(afr[mi], bfr[ni], acc[mi][ni]);
    }
  }
  const int ncol0 = nb * 128 + (W >> 1) * 64;
  float bm[4];
#pragma unroll
  for (int ni = 0; ni < 4; ++ni) bm[ni] = bmap[ncol0 + ni * 16 + lm];
  const size_t ob = ((size_t)(t0 + it) * 256 + l * 128) * 512;
#pragma unroll
  for (int mi = 0; mi < 4; ++mi)
#pragma unroll
    for (int ni = 0; ni < 4; ++ni)
#pragma unroll
      for (int r = 0; r < 4; ++r) {
        int row = (W & 1) * 64 + mi * 16 + 4 * lg + r;
        int col = ncol0 + ni * 16 + lm;
        outp[ob + (size_t)row * 512 + col] = sigf(acc[mi][ni][r] + bm[ni]);
      }
}

// ---------------------------------------------------------------------------
extern "C" void kernel_launch(void* const* d_in, const int* in_sizes, int n_in,
                              void* d_out, int out_size, void* d_ws, size_t ws_size,
                              hipStream_t stream)
{
  const float* latent = (const float*)d_in[0];
  const float* Wih0 = (const float*)d_in[1];
  const float* Whh0 = (const float*)d_in[2];
  const float* bih0 = (const float*)d_in[3];
  const float* bhh0 = (const float*)d_in[4];
  const float* Wih1 = (const float*)d_in[5];
  const float* Whh1 = (const float*)d_in[6];
  const float* bih1 = (const float*)d_in[7];
  const float* bhh1 = (const float*)d_in[8];
  const float* Wmap = (const float*)d_in[9];
  const float* bmap = (const float*)d_in[10];

  char* ws = (char*)d_ws;
  u16* Whh0b  = (u16*)(ws + 0);
  u16* Wih1b  = (u16*)(ws + 524288);
  u16* Whh1b  = (u16*)(ws + 1048576);
  u16* Wmapb  = (u16*)(ws + 1572864);
  float* pre0 = (float*)(ws + 2621440);
  float* bias1= (float*)(ws + 3670016);
  float* h0g  = (float*)(ws + 3674112);
  float* c0g  = (float*)(ws + 3936256);
  float* h1g  = (float*)(ws + 4198400);
  float* c1g  = (float*)(ws + 4460544);
  u32* flags  = (u32*)(ws + 4722688);   // 4096 u32 (16 KB)
  u32* S0     = (u32*)(ws + 4739072);

  long long avail = (long long)ws_size - 4739072LL;
  int TR = (int)(avail / 524288LL);  // bytes per step for S0+S1 (2 x 256 KB)
  if (TR > 512) TR = 512;
  if (TR < 1) TR = 1;
  u32* S1 = S0 + (size_t)TR * 65536;
  float* outp = (float*)d_out;

  prep_kernel<<<dim3(512), dim3(512), 0, stream>>>(
      latent, Wih0, Whh0, bih0, bhh0, Wih1, Whh1, bih1, bhh1, Wmap,
      Whh0b, Wih1b, Whh1b, Wmapb, pre0, bias1, h0g, c0g, h1g, c1g, flags);

  for (int t0p = 0; t0p < 512; t0p += TR) {
    int Tc = (512 - t0p < TR) ? (512 - t0p) : TR;
    void* args[] = {(void*)&Whh0b, (void*)&Wih1b, (void*)&Whh1b, (void*)&pre0,
                    (void*)&bias1, (void*)&h0g, (void*)&c0g, (void*)&h1g,
                    (void*)&c1g, (void*)&S0, (void*)&S1, (void*)&flags,
                    (void*)&t0p, (void*)&Tc};
    hipError_t err = hipLaunchCooperativeKernel((const void*)recur_kernel,
                                                dim3(96), dim3(512), args, 0, stream);
    if (err != hipSuccess) {
      (void)hipGetLastError();  // clear error state
      recur_kernel<<<dim3(96), dim3(512), 0, stream>>>(
          Whh0b, Wih1b, Whh1b, pre0, bias1, h0g, c0g, h1g, c1g, S0, S1, flags, t0p, Tc);
    }
    cmap_kernel<<<dim3(8 * Tc), dim3(256), 0, stream>>>(
        S0, S1, Wmapb, bmap, outp, t0p, Tc);
  }
}